// Round 2
// baseline (3722.975 us; speedup 1.0000x reference)
//
#include <hip/hip_runtime.h>
#include <cstdint>

// Problem constants
#define B_   8
#define ROI_ 90
#define T_   200
#define H_   3
#define F_   64
#define DH_  64
#define R_   270
#define NBN  144000.0f   // B*ROI*T samples per BN channel
#define GSTEP (270ull * 8 * 192)

__device__ __forceinline__ float elu_f(float x) { return x > 0.f ? x : expm1f(x); }
__device__ __forceinline__ float sigm_f(float x) { return 1.f / (1.f + __expf(-x)); }
__device__ __forceinline__ float tanh_f(float x) {
    float xc = fminf(fmaxf(x, -30.f), 30.f);
    float e = __expf(-2.f * xc);
    return (1.f - e) / (1.f + e);
}
__device__ __forceinline__ void fma4(float4& acc, float s, const float4 v) {
    acc.x = fmaf(s, v.x, acc.x); acc.y = fmaf(s, v.y, acc.y);
    acc.z = fmaf(s, v.z, acc.z); acc.w = fmaf(s, v.w, acc.w);
}
__device__ __forceinline__ float dot4(const float4 a, const float4 b) {
    return fmaf(a.x, b.x, fmaf(a.y, b.y, fmaf(a.z, b.z, a.w * b.w)));
}

// ---------------------------------------------------------------------------
// K1: per-(b,t,h): v = mask@x + eps*x ; z1pre = v@W1 + b1 ; BN1 stat partials
// grid 4800 (b*t*h), block 256
// ---------------------------------------------------------------------------
__global__ __launch_bounds__(256) void k_layer1(
    const float* __restrict__ x, const float* __restrict__ a,
    const float* __restrict__ eps_param, const float* __restrict__ W1,
    const float* __restrict__ b1, float* __restrict__ zbuf,
    float* __restrict__ sum1, float* __restrict__ sq1)
{
    __shared__ __align__(16) char smem[16384 + 26112 + 17280];
    float* wlds = (float*)smem;                                   // [f][g] stride 64
    float* xsv  = (float*)(smem + 16384);                         // [96][68]
    unsigned short* msk = (unsigned short*)(smem + 16384 + 26112);// [96][90] bf16 0/1
    float* red = (float*)msk;                                     // reused after matmul

    int bid = blockIdx.x;
    int h = bid % 3;
    int t = (bid / 3) % 200;
    int b = bid / 600;
    int tid = threadIdx.x;

    {
        const float4* wsrc = (const float4*)(W1 + h * 4096);
        for (int idx = tid; idx < 1024; idx += 256)
            *(float4*)&wlds[idx * 4] = wsrc[idx];
    }
    {
        size_t xb = ((((size_t)b * 90) * 200 + t) * 3 + h) * 64;
        for (int idx = tid; idx < 1440; idx += 256) {
            int j = idx >> 4, fq = idx & 15;
            float4 v = *(const float4*)(x + xb + (size_t)j * 38400 + fq * 4);
            *(float4*)&xsv[j * 68 + fq * 4] = v;
        }
    }
    {
        size_t ab = ((((size_t)b * 90) * 200 + t) * 3 + h) * 90;
        for (int idx = tid; idx < 8640; idx += 256) {
            int i = idx / 90, j = idx - i * 90;
            unsigned short mv = 0;
            if (i < 90) {
                float av = a[ab + (size_t)i * 54000 + j];
                mv = (av != 0.f) ? (unsigned short)0x3F80 : (unsigned short)0;
            }
            msk[idx] = mv;
        }
    }
    __syncthreads();

    int fg = tid & 15, ig = tid >> 4;
    int f0 = fg * 4;
    float4 acc[6];
#pragma unroll
    for (int k = 0; k < 6; k++) acc[k] = make_float4(0.f, 0.f, 0.f, 0.f);
    for (int j = 0; j < 90; j++) {
        float4 xv = *(float4*)&xsv[j * 68 + f0];
#pragma unroll
        for (int k = 0; k < 6; k++) {
            unsigned int mb = msk[(ig + 16 * k) * 90 + j];
            float m = __uint_as_float(mb << 16);
            fma4(acc[k], m, xv);
        }
    }
    float ep = eps_param[h];
#pragma unroll
    for (int k = 0; k < 6; k++) {
        int i = ig + 16 * k;
        if (i < 90) {
            float4 xv = *(float4*)&xsv[i * 68 + f0];
            fma4(acc[k], ep, xv);
        }
    }
    __syncthreads();
#pragma unroll
    for (int k = 0; k < 6; k++) {
        int i = ig + 16 * k;
        if (i < 90) *(float4*)&xsv[i * 68 + f0] = acc[k];
    }
    __syncthreads();

    int gg = tid & 15, im = tid >> 4;
    int g0 = gg * 4;
    float4 bv = *(const float4*)(b1 + h * 64 + g0);
    float4 z[6];
#pragma unroll
    for (int k = 0; k < 6; k++) z[k] = bv;
    for (int fq = 0; fq < 16; fq++) {
        float4 wv0 = *(float4*)&wlds[(fq * 4 + 0) * 64 + g0];
        float4 wv1 = *(float4*)&wlds[(fq * 4 + 1) * 64 + g0];
        float4 wv2 = *(float4*)&wlds[(fq * 4 + 2) * 64 + g0];
        float4 wv3 = *(float4*)&wlds[(fq * 4 + 3) * 64 + g0];
#pragma unroll
        for (int k = 0; k < 6; k++) {
            float4 vv = *(float4*)&xsv[(im + 16 * k) * 68 + fq * 4];
            fma4(z[k], vv.x, wv0); fma4(z[k], vv.y, wv1);
            fma4(z[k], vv.z, wv2); fma4(z[k], vv.w, wv3);
        }
    }
    float4 s = make_float4(0, 0, 0, 0), s2 = make_float4(0, 0, 0, 0);
    size_t zb = ((((size_t)b * 90) * 200 + t) * 3 + h) * 64;
#pragma unroll
    for (int k = 0; k < 6; k++) {
        int i = im + 16 * k;
        if (i < 90) {
            *(float4*)(zbuf + zb + (size_t)i * 38400 + g0) = z[k];
            s.x += z[k].x; s.y += z[k].y; s.z += z[k].z; s.w += z[k].w;
            s2.x += z[k].x * z[k].x; s2.y += z[k].y * z[k].y;
            s2.z += z[k].z * z[k].z; s2.w += z[k].w * z[k].w;
        }
    }
    *(float4*)&red[im * 64 + g0] = s;
    *(float4*)&red[1024 + im * 64 + g0] = s2;
    __syncthreads();
    if (tid < 64) {
        float S = 0.f, S2 = 0.f;
        for (int q = 0; q < 16; q++) { S += red[q * 64 + tid]; S2 += red[1024 + q * 64 + tid]; }
        atomicAdd(&sum1[h * 64 + tid], S);
        atomicAdd(&sq1[h * 64 + tid], S2);
    }
}

// ---------------------------------------------------------------------------
// K2: finalize BN stats -> fused scale/shift
// ---------------------------------------------------------------------------
__global__ void k_bnfin(const float* __restrict__ sum, const float* __restrict__ sq,
                        const float* __restrict__ g, const float* __restrict__ be,
                        float* __restrict__ scale, float* __restrict__ shift)
{
    int c = threadIdx.x;
    if (c < 192) {
        float mean = sum[c] / NBN;
        float var = fmaxf(sq[c] / NBN - mean * mean, 0.f);
        float inv = rsqrtf(var + 1e-5f);
        float sc = g[c] * inv;
        scale[c] = sc;
        shift[c] = fmaf(-mean, sc, be[c]);
    }
}

// ---------------------------------------------------------------------------
// K3: z = elu(bn1(z1pre)); z2pre = z@W2 + b2 (in-place in zbuf); BN2 partials
// ---------------------------------------------------------------------------
__global__ __launch_bounds__(256) void k_layer2(
    float* zbuf, const float* __restrict__ W2, const float* __restrict__ b2,
    const float* __restrict__ scale1, const float* __restrict__ shift1,
    float* __restrict__ sum2, float* __restrict__ sq2)
{
    __shared__ __align__(16) float wlds[4096];
    __shared__ __align__(16) float zt[96 * 68];
    __shared__ float red[2048];

    int bid = blockIdx.x;
    int h = bid % 3;
    int t = (bid / 3) % 200;
    int b = bid / 600;
    int tid = threadIdx.x;

    {
        const float4* wsrc = (const float4*)(W2 + h * 4096);
        for (int idx = tid; idx < 1024; idx += 256)
            *(float4*)&wlds[idx * 4] = wsrc[idx];
    }
    size_t zb = ((((size_t)b * 90) * 200 + t) * 3 + h) * 64;
    for (int idx = tid; idx < 1440; idx += 256) {
        int j = idx >> 4, fq = idx & 15;
        float4 v = *(const float4*)(zbuf + zb + (size_t)j * 38400 + fq * 4);
        float4 sc = *(const float4*)(scale1 + h * 64 + fq * 4);
        float4 sh = *(const float4*)(shift1 + h * 64 + fq * 4);
        v.x = elu_f(fmaf(v.x, sc.x, sh.x));
        v.y = elu_f(fmaf(v.y, sc.y, sh.y));
        v.z = elu_f(fmaf(v.z, sc.z, sh.z));
        v.w = elu_f(fmaf(v.w, sc.w, sh.w));
        *(float4*)&zt[j * 68 + fq * 4] = v;
    }
    __syncthreads();

    int gg = tid & 15, im = tid >> 4;
    int g0 = gg * 4;
    float4 bv = *(const float4*)(b2 + h * 64 + g0);
    float4 z[6];
#pragma unroll
    for (int k = 0; k < 6; k++) z[k] = bv;
    for (int fq = 0; fq < 16; fq++) {
        float4 wv0 = *(float4*)&wlds[(fq * 4 + 0) * 64 + g0];
        float4 wv1 = *(float4*)&wlds[(fq * 4 + 1) * 64 + g0];
        float4 wv2 = *(float4*)&wlds[(fq * 4 + 2) * 64 + g0];
        float4 wv3 = *(float4*)&wlds[(fq * 4 + 3) * 64 + g0];
#pragma unroll
        for (int k = 0; k < 6; k++) {
            float4 vv = *(float4*)&zt[(im + 16 * k) * 68 + fq * 4];
            fma4(z[k], vv.x, wv0); fma4(z[k], vv.y, wv1);
            fma4(z[k], vv.z, wv2); fma4(z[k], vv.w, wv3);
        }
    }
    float4 s = make_float4(0, 0, 0, 0), s2 = make_float4(0, 0, 0, 0);
#pragma unroll
    for (int k = 0; k < 6; k++) {
        int i = im + 16 * k;
        if (i < 90) {
            *(float4*)(zbuf + zb + (size_t)i * 38400 + g0) = z[k];
            s.x += z[k].x; s.y += z[k].y; s.z += z[k].z; s.w += z[k].w;
            s2.x += z[k].x * z[k].x; s2.y += z[k].y * z[k].y;
            s2.z += z[k].z * z[k].z; s2.w += z[k].w * z[k].w;
        }
    }
    *(float4*)&red[im * 64 + g0] = s;
    *(float4*)&red[1024 + im * 64 + g0] = s2;
    __syncthreads();
    if (tid < 64) {
        float S = 0.f, S2 = 0.f;
        for (int q = 0; q < 16; q++) { S += red[q * 64 + tid]; S2 += red[1024 + q * 64 + tid]; }
        atomicAdd(&sum2[h * 64 + tid], S);
        atomicAdd(&sq2[h * 64 + tid], S2);
    }
}

// ---------------------------------------------------------------------------
// K5: z = max(bn2(z2pre), 0) [relu(elu(x)) == max(x,0)];
//     gi[t][r][b][g] = z_row . Wih[r][g][:] + bih[r][g]
// ---------------------------------------------------------------------------
__global__ __launch_bounds__(256) void k_giproj(
    const float* __restrict__ zin, const float* __restrict__ Wih,
    const float* __restrict__ bih, const float* __restrict__ scale2,
    const float* __restrict__ shift2, float* __restrict__ gi)
{
    __shared__ __align__(16) float wl[192 * 68];   // 52224B
    __shared__ __align__(16) float zl[40 * 68];    // 10880B
    __shared__ float bsc[64], bsh[64];

    int bid = blockIdx.x;
    int r = bid >> 2, tq = bid & 3;
    int roi = r / 3, h = r - roi * 3;
    int tid = threadIdx.x;

    if (tid < 64) { bsc[tid] = scale2[h * 64 + tid]; bsh[tid] = shift2[h * 64 + tid]; }
    {
        const float4* wsrc = (const float4*)(Wih + (size_t)r * 12288);
        for (int idx = tid; idx < 3072; idx += 256) {
            int g = idx >> 4, fq = idx & 15;
            *(float4*)&wl[g * 68 + fq * 4] = wsrc[idx];
        }
    }
    int gg = tid & 31, rg = tid >> 5;
    float bihv[6];
#pragma unroll
    for (int k = 0; k < 6; k++) bihv[k] = bih[r * 192 + gg + 32 * k];

    for (int ci = 0; ci < 10; ci++) {
        int t0 = tq * 50 + ci * 5;
        __syncthreads();
        for (int idx = tid; idx < 640; idx += 256) {
            int row = idx >> 4, fq = idx & 15;
            int dt = row >> 3, bb = row & 7;
            size_t addr = ((((size_t)bb * 90 + roi) * 200 + (t0 + dt)) * 3 + h) * 64 + fq * 4;
            float4 v = *(const float4*)(zin + addr);
            float4 sc = *(const float4*)&bsc[fq * 4];
            float4 sh = *(const float4*)&bsh[fq * 4];
            v.x = fmaxf(fmaf(v.x, sc.x, sh.x), 0.f);
            v.y = fmaxf(fmaf(v.y, sc.y, sh.y), 0.f);
            v.z = fmaxf(fmaf(v.z, sc.z, sh.z), 0.f);
            v.w = fmaxf(fmaf(v.w, sc.w, sh.w), 0.f);
            *(float4*)&zl[row * 68 + fq * 4] = v;
        }
        __syncthreads();
        float acc[6][5];
#pragma unroll
        for (int k = 0; k < 6; k++)
#pragma unroll
            for (int rr = 0; rr < 5; rr++) acc[k][rr] = 0.f;
        for (int fq = 0; fq < 16; fq++) {
            float4 wv[6];
#pragma unroll
            for (int k = 0; k < 6; k++) wv[k] = *(float4*)&wl[(gg + 32 * k) * 68 + fq * 4];
#pragma unroll
            for (int rr = 0; rr < 5; rr++) {
                float4 zv = *(float4*)&zl[(rg * 5 + rr) * 68 + fq * 4];
#pragma unroll
                for (int k = 0; k < 6; k++) {
                    acc[k][rr] = fmaf(zv.x, wv[k].x, acc[k][rr]);
                    acc[k][rr] = fmaf(zv.y, wv[k].y, acc[k][rr]);
                    acc[k][rr] = fmaf(zv.z, wv[k].z, acc[k][rr]);
                    acc[k][rr] = fmaf(zv.w, wv[k].w, acc[k][rr]);
                }
            }
        }
#pragma unroll
        for (int rr = 0; rr < 5; rr++) {
            int row = rg * 5 + rr; int dt = row >> 3, bb = row & 7;
            size_t gb = (((size_t)(t0 + dt) * 270 + r) * 8 + bb) * 192 + gg;
#pragma unroll
            for (int k = 0; k < 6; k++) gi[gb + 32 * k] = acc[k][rr] + bihv[k];
        }
    }
}

// ---------------------------------------------------------------------------
// K6: GRU scan — ONE WAVE PER (r,b), zero barriers in the 200-step loop.
// Lane L owns Whh rows {L, L+64, L+128} in registers (48 float4). h broadcast
// via per-wave private LDS buffer (same-wave ds ordering, no __syncthreads).
// gi for t+1 software-pipelined. Block = 4 waves sharing one r (Whh staging).
// grid 540 (r x batch-quad), block 256, 2 waves/SIMD.
// ---------------------------------------------------------------------------
__global__ __launch_bounds__(256, 2) void k_gru(
    const float* __restrict__ gi, const float* __restrict__ Whh,
    const float* __restrict__ bhh, float* __restrict__ out)
{
    __shared__ __align__(16) float stg[64 * 68];   // Whh staging, 17408B
    __shared__ __align__(16) float hbuf[4][64];    // per-wave h

    int bid = blockIdx.x;
    int r = bid >> 1, bq = bid & 1;
    int roi = r / 3, h = r - roi * 3;
    int tid = threadIdx.x;
    int w = tid >> 6, l = tid & 63;
    int b = bq * 4 + w;

    // --- stage Whh[r] -> registers, 3 chunks of 64 rows (one per gate) ---
    float4 wreg[3][16];
    const float4* wsrc = (const float4*)(Whh + (size_t)r * 12288);
#pragma unroll
    for (int c = 0; c < 3; c++) {
        __syncthreads();
        for (int idx = tid; idx < 1024; idx += 256) {
            int gl = idx >> 4, fq = idx & 15;
            *(float4*)&stg[gl * 68 + fq * 4] = wsrc[c * 1024 + idx];
        }
        __syncthreads();
#pragma unroll
        for (int q = 0; q < 16; q++)
            wreg[c][q] = *(float4*)&stg[l * 68 + q * 4];
    }

    float bh0 = bhh[r * 192 + l];
    float bh1 = bhh[r * 192 + 64 + l];
    float bh2 = bhh[r * 192 + 128 + l];

    const float* gp0 = gi + ((size_t)r * 8 + b) * 192 + l;
    float* op = out + ((((size_t)b * 90 + roi) * 200) * 3 + h) * 64 + l;

    hbuf[w][l] = 0.f;
    float hreg = 0.f;

    // preload gi for t=0
    float gr = gp0[0], gz = gp0[64], gn = gp0[128];

    for (int t = 0; t < 200; t++) {
        // gh dots: 3 gates x 64-d, h broadcast from per-wave LDS
        float s0 = 0.f, s1 = 0.f, s2 = 0.f, s3 = 0.f, s4 = 0.f, s5 = 0.f;
#pragma unroll
        for (int q = 0; q < 16; q += 2) {
            float4 h0 = *(float4*)&hbuf[w][q * 4];
            float4 h1 = *(float4*)&hbuf[w][q * 4 + 4];
            s0 += dot4(wreg[0][q], h0); s1 += dot4(wreg[0][q + 1], h1);
            s2 += dot4(wreg[1][q], h0); s3 += dot4(wreg[1][q + 1], h1);
            s4 += dot4(wreg[2][q], h0); s5 += dot4(wreg[2][q + 1], h1);
        }
        // prefetch gi for t+1 (independent of h-chain)
        float grn = 0.f, gzn = 0.f, gnn = 0.f;
        if (t < 199) {
            const float* gq = gp0 + (size_t)(t + 1) * GSTEP;
            grn = gq[0]; gzn = gq[64]; gnn = gq[128];
        }
        float ghr = s0 + s1 + bh0;
        float ghz = s2 + s3 + bh1;
        float ghn = s4 + s5 + bh2;
        float rr = sigm_f(gr + ghr);
        float uu = sigm_f(gz + ghz);
        float nn = tanh_f(fmaf(rr, ghn, gn));
        hreg = fmaf(uu, hreg - nn, nn);   // (1-u)*n + u*h
        hbuf[w][l] = hreg;
        op[(size_t)t * 192] = hreg;
        gr = grn; gz = gzn; gn = gnn;
    }
}

// ---------------------------------------------------------------------------
extern "C" void kernel_launch(void* const* d_in, const int* in_sizes, int n_in,
                              void* d_out, int out_size, void* d_ws, size_t ws_size,
                              hipStream_t stream)
{
    const float* x   = (const float*)d_in[0];
    const float* a   = (const float*)d_in[1];
    const float* eps = (const float*)d_in[2];
    const float* W1  = (const float*)d_in[3];
    const float* b1  = (const float*)d_in[4];
    const float* g1  = (const float*)d_in[5];
    const float* be1 = (const float*)d_in[6];
    const float* W2  = (const float*)d_in[7];
    const float* b2  = (const float*)d_in[8];
    const float* g2  = (const float*)d_in[9];
    const float* be2 = (const float*)d_in[10];
    const float* Wih = (const float*)d_in[11];
    const float* Whh = (const float*)d_in[12];
    const float* bih = (const float*)d_in[13];
    const float* bhh = (const float*)d_in[14];
    float* out = (float*)d_out;

    float* wsf = (float*)d_ws;
    float* sum1 = wsf,        *sq1 = wsf + 192;
    float* sum2 = wsf + 384,  *sq2 = wsf + 576;
    float* scale1 = wsf + 768,  *shift1 = wsf + 960;
    float* scale2 = wsf + 1152, *shift2 = wsf + 1344;
    float* zbuf = wsf + 2048;                 // 27,648,000 floats
    float* gi   = zbuf + 27648000ull;         // 82,944,000 floats

    hipMemsetAsync(wsf, 0, 768 * sizeof(float), stream);
    hipLaunchKernelGGL(k_layer1, dim3(4800), dim3(256), 0, stream,
                       x, a, eps, W1, b1, zbuf, sum1, sq1);
    hipLaunchKernelGGL(k_bnfin, dim3(1), dim3(256), 0, stream,
                       sum1, sq1, g1, be1, scale1, shift1);
    hipLaunchKernelGGL(k_layer2, dim3(4800), dim3(256), 0, stream,
                       zbuf, W2, b2, scale1, shift1, sum2, sq2);
    hipLaunchKernelGGL(k_bnfin, dim3(1), dim3(256), 0, stream,
                       sum2, sq2, g2, be2, scale2, shift2);
    hipLaunchKernelGGL(k_giproj, dim3(1080), dim3(256), 0, stream,
                       zbuf, Wih, bih, scale2, shift2, gi);
    hipLaunchKernelGGL(k_gru, dim3(540), dim3(256), 0, stream,
                       gi, Whh, bhh, out);
}

// Round 3
// 1373.094 us; speedup vs baseline: 2.7114x; 2.7114x over previous
//
#include <hip/hip_runtime.h>
#include <cstdint>

// Problem constants
#define B_   8
#define ROI_ 90
#define T_   200
#define H_   3
#define F_   64
#define DH_  64
#define R_   270
#define NBN  144000.0f   // B*ROI*T samples per BN channel
#define GSTEP (270ull * 8 * 192)

__device__ __forceinline__ float elu_f(float x) { return x > 0.f ? x : expm1f(x); }
__device__ __forceinline__ float sigm_f(float x) { return 1.f / (1.f + __expf(-x)); }
__device__ __forceinline__ float tanh_f(float x) {
    float xc = fminf(fmaxf(x, -30.f), 30.f);
    float e = __expf(-2.f * xc);
    return (1.f - e) / (1.f + e);
}
__device__ __forceinline__ void fma4(float4& acc, float s, const float4 v) {
    acc.x = fmaf(s, v.x, acc.x); acc.y = fmaf(s, v.y, acc.y);
    acc.z = fmaf(s, v.z, acc.z); acc.w = fmaf(s, v.w, acc.w);
}
__device__ __forceinline__ float dot4(const float4 a, const float4 b) {
    return fmaf(a.x, b.x, fmaf(a.y, b.y, fmaf(a.z, b.z, a.w * b.w)));
}

// ---------------------------------------------------------------------------
// K1: per-(b,t,h): v = mask@x + eps*x ; z1pre = v@W1 + b1 ; BN1 stat partials
// grid 4800 (b*t*h), block 256
// ---------------------------------------------------------------------------
__global__ __launch_bounds__(256) void k_layer1(
    const float* __restrict__ x, const float* __restrict__ a,
    const float* __restrict__ eps_param, const float* __restrict__ W1,
    const float* __restrict__ b1, float* __restrict__ zbuf,
    float* __restrict__ sum1, float* __restrict__ sq1)
{
    __shared__ __align__(16) char smem[16384 + 26112 + 17280];
    float* wlds = (float*)smem;                                   // [f][g] stride 64
    float* xsv  = (float*)(smem + 16384);                         // [96][68]
    unsigned short* msk = (unsigned short*)(smem + 16384 + 26112);// [96][90] bf16 0/1
    float* red = (float*)msk;                                     // reused after matmul

    int bid = blockIdx.x;
    int h = bid % 3;
    int t = (bid / 3) % 200;
    int b = bid / 600;
    int tid = threadIdx.x;

    {
        const float4* wsrc = (const float4*)(W1 + h * 4096);
        for (int idx = tid; idx < 1024; idx += 256)
            *(float4*)&wlds[idx * 4] = wsrc[idx];
    }
    {
        size_t xb = ((((size_t)b * 90) * 200 + t) * 3 + h) * 64;
        for (int idx = tid; idx < 1440; idx += 256) {
            int j = idx >> 4, fq = idx & 15;
            float4 v = *(const float4*)(x + xb + (size_t)j * 38400 + fq * 4);
            *(float4*)&xsv[j * 68 + fq * 4] = v;
        }
    }
    {
        size_t ab = ((((size_t)b * 90) * 200 + t) * 3 + h) * 90;
        for (int idx = tid; idx < 8640; idx += 256) {
            int i = idx / 90, j = idx - i * 90;
            unsigned short mv = 0;
            if (i < 90) {
                float av = a[ab + (size_t)i * 54000 + j];
                mv = (av != 0.f) ? (unsigned short)0x3F80 : (unsigned short)0;
            }
            msk[idx] = mv;
        }
    }
    __syncthreads();

    int fg = tid & 15, ig = tid >> 4;
    int f0 = fg * 4;
    float4 acc[6];
#pragma unroll
    for (int k = 0; k < 6; k++) acc[k] = make_float4(0.f, 0.f, 0.f, 0.f);
    for (int j = 0; j < 90; j++) {
        float4 xv = *(float4*)&xsv[j * 68 + f0];
#pragma unroll
        for (int k = 0; k < 6; k++) {
            unsigned int mb = msk[(ig + 16 * k) * 90 + j];
            float m = __uint_as_float(mb << 16);
            fma4(acc[k], m, xv);
        }
    }
    float ep = eps_param[h];
#pragma unroll
    for (int k = 0; k < 6; k++) {
        int i = ig + 16 * k;
        if (i < 90) {
            float4 xv = *(float4*)&xsv[i * 68 + f0];
            fma4(acc[k], ep, xv);
        }
    }
    __syncthreads();
#pragma unroll
    for (int k = 0; k < 6; k++) {
        int i = ig + 16 * k;
        if (i < 90) *(float4*)&xsv[i * 68 + f0] = acc[k];
    }
    __syncthreads();

    int gg = tid & 15, im = tid >> 4;
    int g0 = gg * 4;
    float4 bv = *(const float4*)(b1 + h * 64 + g0);
    float4 z[6];
#pragma unroll
    for (int k = 0; k < 6; k++) z[k] = bv;
    for (int fq = 0; fq < 16; fq++) {
        float4 wv0 = *(float4*)&wlds[(fq * 4 + 0) * 64 + g0];
        float4 wv1 = *(float4*)&wlds[(fq * 4 + 1) * 64 + g0];
        float4 wv2 = *(float4*)&wlds[(fq * 4 + 2) * 64 + g0];
        float4 wv3 = *(float4*)&wlds[(fq * 4 + 3) * 64 + g0];
#pragma unroll
        for (int k = 0; k < 6; k++) {
            float4 vv = *(float4*)&xsv[(im + 16 * k) * 68 + fq * 4];
            fma4(z[k], vv.x, wv0); fma4(z[k], vv.y, wv1);
            fma4(z[k], vv.z, wv2); fma4(z[k], vv.w, wv3);
        }
    }
    float4 s = make_float4(0, 0, 0, 0), s2 = make_float4(0, 0, 0, 0);
    size_t zb = ((((size_t)b * 90) * 200 + t) * 3 + h) * 64;
#pragma unroll
    for (int k = 0; k < 6; k++) {
        int i = im + 16 * k;
        if (i < 90) {
            *(float4*)(zbuf + zb + (size_t)i * 38400 + g0) = z[k];
            s.x += z[k].x; s.y += z[k].y; s.z += z[k].z; s.w += z[k].w;
            s2.x += z[k].x * z[k].x; s2.y += z[k].y * z[k].y;
            s2.z += z[k].z * z[k].z; s2.w += z[k].w * z[k].w;
        }
    }
    *(float4*)&red[im * 64 + g0] = s;
    *(float4*)&red[1024 + im * 64 + g0] = s2;
    __syncthreads();
    if (tid < 64) {
        float S = 0.f, S2 = 0.f;
        for (int q = 0; q < 16; q++) { S += red[q * 64 + tid]; S2 += red[1024 + q * 64 + tid]; }
        atomicAdd(&sum1[h * 64 + tid], S);
        atomicAdd(&sq1[h * 64 + tid], S2);
    }
}

// ---------------------------------------------------------------------------
// K2: finalize BN stats -> fused scale/shift
// ---------------------------------------------------------------------------
__global__ void k_bnfin(const float* __restrict__ sum, const float* __restrict__ sq,
                        const float* __restrict__ g, const float* __restrict__ be,
                        float* __restrict__ scale, float* __restrict__ shift)
{
    int c = threadIdx.x;
    if (c < 192) {
        float mean = sum[c] / NBN;
        float var = fmaxf(sq[c] / NBN - mean * mean, 0.f);
        float inv = rsqrtf(var + 1e-5f);
        float sc = g[c] * inv;
        scale[c] = sc;
        shift[c] = fmaf(-mean, sc, be[c]);
    }
}

// ---------------------------------------------------------------------------
// K3: z = elu(bn1(z1pre)); z2pre = z@W2 + b2 (in-place in zbuf); BN2 partials
// ---------------------------------------------------------------------------
__global__ __launch_bounds__(256) void k_layer2(
    float* zbuf, const float* __restrict__ W2, const float* __restrict__ b2,
    const float* __restrict__ scale1, const float* __restrict__ shift1,
    float* __restrict__ sum2, float* __restrict__ sq2)
{
    __shared__ __align__(16) float wlds[4096];
    __shared__ __align__(16) float zt[96 * 68];
    __shared__ float red[2048];

    int bid = blockIdx.x;
    int h = bid % 3;
    int t = (bid / 3) % 200;
    int b = bid / 600;
    int tid = threadIdx.x;

    {
        const float4* wsrc = (const float4*)(W2 + h * 4096);
        for (int idx = tid; idx < 1024; idx += 256)
            *(float4*)&wlds[idx * 4] = wsrc[idx];
    }
    size_t zb = ((((size_t)b * 90) * 200 + t) * 3 + h) * 64;
    for (int idx = tid; idx < 1440; idx += 256) {
        int j = idx >> 4, fq = idx & 15;
        float4 v = *(const float4*)(zbuf + zb + (size_t)j * 38400 + fq * 4);
        float4 sc = *(const float4*)(scale1 + h * 64 + fq * 4);
        float4 sh = *(const float4*)(shift1 + h * 64 + fq * 4);
        v.x = elu_f(fmaf(v.x, sc.x, sh.x));
        v.y = elu_f(fmaf(v.y, sc.y, sh.y));
        v.z = elu_f(fmaf(v.z, sc.z, sh.z));
        v.w = elu_f(fmaf(v.w, sc.w, sh.w));
        *(float4*)&zt[j * 68 + fq * 4] = v;
    }
    __syncthreads();

    int gg = tid & 15, im = tid >> 4;
    int g0 = gg * 4;
    float4 bv = *(const float4*)(b2 + h * 64 + g0);
    float4 z[6];
#pragma unroll
    for (int k = 0; k < 6; k++) z[k] = bv;
    for (int fq = 0; fq < 16; fq++) {
        float4 wv0 = *(float4*)&wlds[(fq * 4 + 0) * 64 + g0];
        float4 wv1 = *(float4*)&wlds[(fq * 4 + 1) * 64 + g0];
        float4 wv2 = *(float4*)&wlds[(fq * 4 + 2) * 64 + g0];
        float4 wv3 = *(float4*)&wlds[(fq * 4 + 3) * 64 + g0];
#pragma unroll
        for (int k = 0; k < 6; k++) {
            float4 vv = *(float4*)&zt[(im + 16 * k) * 68 + fq * 4];
            fma4(z[k], vv.x, wv0); fma4(z[k], vv.y, wv1);
            fma4(z[k], vv.z, wv2); fma4(z[k], vv.w, wv3);
        }
    }
    float4 s = make_float4(0, 0, 0, 0), s2 = make_float4(0, 0, 0, 0);
#pragma unroll
    for (int k = 0; k < 6; k++) {
        int i = im + 16 * k;
        if (i < 90) {
            *(float4*)(zbuf + zb + (size_t)i * 38400 + g0) = z[k];
            s.x += z[k].x; s.y += z[k].y; s.z += z[k].z; s.w += z[k].w;
            s2.x += z[k].x * z[k].x; s2.y += z[k].y * z[k].y;
            s2.z += z[k].z * z[k].z; s2.w += z[k].w * z[k].w;
        }
    }
    *(float4*)&red[im * 64 + g0] = s;
    *(float4*)&red[1024 + im * 64 + g0] = s2;
    __syncthreads();
    if (tid < 64) {
        float S = 0.f, S2 = 0.f;
        for (int q = 0; q < 16; q++) { S += red[q * 64 + tid]; S2 += red[1024 + q * 64 + tid]; }
        atomicAdd(&sum2[h * 64 + tid], S);
        atomicAdd(&sq2[h * 64 + tid], S2);
    }
}

// ---------------------------------------------------------------------------
// K5: z = max(bn2(z2pre), 0) [relu(elu(x)) == max(x,0)];
//     gi[t][r][b][g] = z_row . Wih[r][g][:] + bih[r][g]
// ---------------------------------------------------------------------------
__global__ __launch_bounds__(256) void k_giproj(
    const float* __restrict__ zin, const float* __restrict__ Wih,
    const float* __restrict__ bih, const float* __restrict__ scale2,
    const float* __restrict__ shift2, float* __restrict__ gi)
{
    __shared__ __align__(16) float wl[192 * 68];   // 52224B
    __shared__ __align__(16) float zl[40 * 68];    // 10880B
    __shared__ float bsc[64], bsh[64];

    int bid = blockIdx.x;
    int r = bid >> 2, tq = bid & 3;
    int roi = r / 3, h = r - roi * 3;
    int tid = threadIdx.x;

    if (tid < 64) { bsc[tid] = scale2[h * 64 + tid]; bsh[tid] = shift2[h * 64 + tid]; }
    {
        const float4* wsrc = (const float4*)(Wih + (size_t)r * 12288);
        for (int idx = tid; idx < 3072; idx += 256) {
            int g = idx >> 4, fq = idx & 15;
            *(float4*)&wl[g * 68 + fq * 4] = wsrc[idx];
        }
    }
    int gg = tid & 31, rg = tid >> 5;
    float bihv[6];
#pragma unroll
    for (int k = 0; k < 6; k++) bihv[k] = bih[r * 192 + gg + 32 * k];

    for (int ci = 0; ci < 10; ci++) {
        int t0 = tq * 50 + ci * 5;
        __syncthreads();
        for (int idx = tid; idx < 640; idx += 256) {
            int row = idx >> 4, fq = idx & 15;
            int dt = row >> 3, bb = row & 7;
            size_t addr = ((((size_t)bb * 90 + roi) * 200 + (t0 + dt)) * 3 + h) * 64 + fq * 4;
            float4 v = *(const float4*)(zin + addr);
            float4 sc = *(const float4*)&bsc[fq * 4];
            float4 sh = *(const float4*)&bsh[fq * 4];
            v.x = fmaxf(fmaf(v.x, sc.x, sh.x), 0.f);
            v.y = fmaxf(fmaf(v.y, sc.y, sh.y), 0.f);
            v.z = fmaxf(fmaf(v.z, sc.z, sh.z), 0.f);
            v.w = fmaxf(fmaf(v.w, sc.w, sh.w), 0.f);
            *(float4*)&zl[row * 68 + fq * 4] = v;
        }
        __syncthreads();
        float acc[6][5];
#pragma unroll
        for (int k = 0; k < 6; k++)
#pragma unroll
            for (int rr = 0; rr < 5; rr++) acc[k][rr] = 0.f;
        for (int fq = 0; fq < 16; fq++) {
            float4 wv[6];
#pragma unroll
            for (int k = 0; k < 6; k++) wv[k] = *(float4*)&wl[(gg + 32 * k) * 68 + fq * 4];
#pragma unroll
            for (int rr = 0; rr < 5; rr++) {
                float4 zv = *(float4*)&zl[(rg * 5 + rr) * 68 + fq * 4];
#pragma unroll
                for (int k = 0; k < 6; k++) {
                    acc[k][rr] = fmaf(zv.x, wv[k].x, acc[k][rr]);
                    acc[k][rr] = fmaf(zv.y, wv[k].y, acc[k][rr]);
                    acc[k][rr] = fmaf(zv.z, wv[k].z, acc[k][rr]);
                    acc[k][rr] = fmaf(zv.w, wv[k].w, acc[k][rr]);
                }
            }
        }
#pragma unroll
        for (int rr = 0; rr < 5; rr++) {
            int row = rg * 5 + rr; int dt = row >> 3, bb = row & 7;
            size_t gb = (((size_t)(t0 + dt) * 270 + r) * 8 + bb) * 192 + gg;
#pragma unroll
            for (int k = 0; k < 6; k++) gi[gb + 32 * k] = acc[k][rr] + bihv[k];
        }
    }
}

// ---------------------------------------------------------------------------
// K6: GRU scan — one wave per (r,b). grid 2160 x 64 threads.
// Lane l owns Whh rows {l, 64+l, 128+l} as three NAMED float4[16] arrays,
// loaded DIRECTLY global->reg (no LDS staging, no barriers, all indices
// compile-time) so they cannot be demoted to scratch (round-2 failure).
// h broadcast via per-block (= per-wave) LDS; same-wave DS order, no barrier.
// __launch_bounds__(64,2): VGPR cap 256, need ~215 -> 2 waves/SIMD.
// ---------------------------------------------------------------------------
__global__ __launch_bounds__(64, 2) void k_gru(
    const float* __restrict__ gi, const float* __restrict__ Whh,
    const float* __restrict__ bhh, float* __restrict__ out)
{
    __shared__ __align__(16) float hb[64];

    int bid = blockIdx.x;            // r*8 + b
    int r = bid >> 3, b = bid & 7;
    int roi = r / 3, h = r - roi * 3;
    int l = threadIdx.x;             // 0..63

    const float4* w0 = (const float4*)(Whh + (size_t)r * 12288 + (size_t)(l) * 64);
    const float4* w1 = (const float4*)(Whh + (size_t)r * 12288 + (size_t)(64 + l) * 64);
    const float4* w2 = (const float4*)(Whh + (size_t)r * 12288 + (size_t)(128 + l) * 64);
    float4 wr[16], wz[16], wn[16];
#pragma unroll
    for (int q = 0; q < 16; q++) { wr[q] = w0[q]; }
#pragma unroll
    for (int q = 0; q < 16; q++) { wz[q] = w1[q]; }
#pragma unroll
    for (int q = 0; q < 16; q++) { wn[q] = w2[q]; }

    float bhr = bhh[r * 192 + l];
    float bhz = bhh[r * 192 + 64 + l];
    float bhn = bhh[r * 192 + 128 + l];

    const float* gp = gi + ((size_t)r * 8 + b) * 192 + l;
    float* op = out + ((((size_t)b * 90 + roi) * 200) * 3 + h) * 64 + l;

    hb[l] = 0.f;
    float hreg = 0.f;
    float gr = gp[0], gz = gp[64], gn = gp[128];

    for (int t = 0; t < 200; t++) {
        float ar = 0.f, az = 0.f, an = 0.f;
#pragma unroll
        for (int q = 0; q < 16; q++) {
            float4 hv = *(float4*)&hb[q * 4];
            ar += dot4(wr[q], hv);
            az += dot4(wz[q], hv);
            an += dot4(wn[q], hv);
        }
        // prefetch gi for t+1 (independent of the h-chain)
        float grn = 0.f, gzn = 0.f, gnn = 0.f;
        if (t < 199) {
            const float* gq = gp + (size_t)(t + 1) * GSTEP;
            grn = gq[0]; gzn = gq[64]; gnn = gq[128];
        }
        float rr = sigm_f(gr + ar + bhr);
        float uu = sigm_f(gz + az + bhz);
        float nn = tanh_f(fmaf(rr, an + bhn, gn));
        hreg = fmaf(uu, hreg - nn, nn);     // (1-u)*n + u*h
        hb[l] = hreg;
        op[(size_t)t * 192] = hreg;
        gr = grn; gz = gzn; gn = gnn;
    }
}

// ---------------------------------------------------------------------------
extern "C" void kernel_launch(void* const* d_in, const int* in_sizes, int n_in,
                              void* d_out, int out_size, void* d_ws, size_t ws_size,
                              hipStream_t stream)
{
    const float* x   = (const float*)d_in[0];
    const float* a   = (const float*)d_in[1];
    const float* eps = (const float*)d_in[2];
    const float* W1  = (const float*)d_in[3];
    const float* b1  = (const float*)d_in[4];
    const float* g1  = (const float*)d_in[5];
    const float* be1 = (const float*)d_in[6];
    const float* W2  = (const float*)d_in[7];
    const float* b2  = (const float*)d_in[8];
    const float* g2  = (const float*)d_in[9];
    const float* be2 = (const float*)d_in[10];
    const float* Wih = (const float*)d_in[11];
    const float* Whh = (const float*)d_in[12];
    const float* bih = (const float*)d_in[13];
    const float* bhh = (const float*)d_in[14];
    float* out = (float*)d_out;

    float* wsf = (float*)d_ws;
    float* sum1 = wsf,        *sq1 = wsf + 192;
    float* sum2 = wsf + 384,  *sq2 = wsf + 576;
    float* scale1 = wsf + 768,  *shift1 = wsf + 960;
    float* scale2 = wsf + 1152, *shift2 = wsf + 1344;
    float* zbuf = wsf + 2048;                 // 27,648,000 floats
    float* gi   = zbuf + 27648000ull;         // 82,944,000 floats

    hipMemsetAsync(wsf, 0, 768 * sizeof(float), stream);
    hipLaunchKernelGGL(k_layer1, dim3(4800), dim3(256), 0, stream,
                       x, a, eps, W1, b1, zbuf, sum1, sq1);
    hipLaunchKernelGGL(k_bnfin, dim3(1), dim3(256), 0, stream,
                       sum1, sq1, g1, be1, scale1, shift1);
    hipLaunchKernelGGL(k_layer2, dim3(4800), dim3(256), 0, stream,
                       zbuf, W2, b2, scale1, shift1, sum2, sq2);
    hipLaunchKernelGGL(k_bnfin, dim3(1), dim3(256), 0, stream,
                       sum2, sq2, g2, be2, scale2, shift2);
    hipLaunchKernelGGL(k_giproj, dim3(1080), dim3(256), 0, stream,
                       zbuf, Wih, bih, scale2, shift2, gi);
    hipLaunchKernelGGL(k_gru, dim3(2160), dim3(64), 0, stream,
                       gi, Whh, bhh, out);
}